// Round 7
// baseline (676.012 us; speedup 1.0000x reference)
//
#include <hip/hip_runtime.h>
#include <hip/hip_bf16.h>
#include <stdint.h>

typedef __hip_bfloat16 bf16_t;
typedef __attribute__((ext_vector_type(8))) short bf16x8;   // 8 bf16 = 4 VGPR
typedef __attribute__((ext_vector_type(4))) float f32x4;

#define DEV static __device__ __forceinline__

constexpr int kBB = 8, kL = 2048, kD = 1024;
constexpr int kM = kBB * kL;   // 16384 rows
constexpr int kSeg = 32, kP = 64;   // WKV: 32 segments x 64 steps

DEV float bf2f(unsigned short u) { return __uint_as_float((unsigned)u << 16); }
DEV unsigned short f2bf(float f) {
  unsigned u = __float_as_uint(f);
  return (unsigned short)((u + 0x7fffu + ((u >> 16) & 1u)) >> 16);  // RNE
}

// async global->LDS, 16B per lane. LDS dest is wave-uniform-base + lane*16.
DEV void gld16(const void* g, void* l) {
  const __attribute__((address_space(1))) unsigned* gp =
      (const __attribute__((address_space(1))) unsigned*)(uintptr_t)g;
  __attribute__((address_space(3))) unsigned* lp =
      (__attribute__((address_space(3))) unsigned*)(unsigned)(uintptr_t)l;
  __builtin_amdgcn_global_load_lds(gp, lp, 16, 0, 0);
}

// ---------------- weight transpose + cast: W[R][C] f32 -> Wt[C][R] bf16 ---------------
__global__ __launch_bounds__(256) void k_transpose_cast(
    const float* __restrict__ W, bf16_t* __restrict__ Wt, int R, int C) {
  __shared__ float tile[32][33];
  const int bx = blockIdx.x * 32;           // C-dim base
  const int by = blockIdx.y * 32;           // R-dim base
  const int tx = threadIdx.x & 31, ty = threadIdx.x >> 5;  // 32 x 8
#pragma unroll
  for (int i = 0; i < 32; i += 8)
    tile[ty + i][tx] = W[(size_t)(by + ty + i) * C + (bx + tx)];
  __syncthreads();
#pragma unroll
  for (int i = 0; i < 32; i += 8)
    Wt[(size_t)(bx + ty + i) * R + (by + tx)] = __float2bfloat16(tile[tx][ty + i]);
}

// ---------------- LayerNorm row stats: one wave per row ----------------
__global__ __launch_bounds__(256) void k_ln_stats(
    const float* __restrict__ X, float* __restrict__ mean, float* __restrict__ rstd) {
  const int row = blockIdx.x * 4 + (threadIdx.x >> 6);
  const int lane = threadIdx.x & 63;
  const float4* xr = (const float4*)(X + (size_t)row * kD);
  float s = 0.f, s2 = 0.f;
#pragma unroll
  for (int i = 0; i < 4; ++i) {
    float4 v = xr[lane + 64 * i];
    s += v.x + v.y + v.z + v.w;
    s2 += v.x * v.x + v.y * v.y + v.z * v.z + v.w * v.w;
  }
#pragma unroll
  for (int off = 32; off > 0; off >>= 1) {
    s += __shfl_xor(s, off);
    s2 += __shfl_xor(s2, off);
  }
  if (lane == 0) {
    float m = s * (1.f / kD);
    float var = fmaxf(s2 * (1.f / kD) - m * m, 0.f);   // biased var
    mean[row] = m;
    rstd[row] = rsqrtf(var + 1e-5f);
  }
}

// ---------------- LN apply + shift + time-mix -> xk/xv/xr (bf16) ----------------
__global__ __launch_bounds__(256) void k_ln_mix1(
    const float* __restrict__ X, const float* __restrict__ mean, const float* __restrict__ rstd,
    const float* __restrict__ g, const float* __restrict__ be,
    const float* __restrict__ mk, const float* __restrict__ mv, const float* __restrict__ mr,
    bf16_t* __restrict__ ok, bf16_t* __restrict__ ov, bf16_t* __restrict__ orr) {
  const int row = blockIdx.x;
  const int l = row & (kL - 1);
  const int i = threadIdx.x;                 // 4 floats per thread
  const bool hp = (l != 0);
  const float m0 = mean[row], s0 = rstd[row];
  const float m1 = hp ? mean[row - 1] : 0.f;
  const float s1 = hp ? rstd[row - 1] : 0.f;
  float xa[4], pa[4] = {0.f, 0.f, 0.f, 0.f}, ga[4], ba[4], ka[4], va[4], ra[4];
  *(float4*)xa = ((const float4*)(X + (size_t)row * kD))[i];
  if (hp) *(float4*)pa = ((const float4*)(X + (size_t)(row - 1) * kD))[i];
  *(float4*)ga = ((const float4*)g)[i];
  *(float4*)ba = ((const float4*)be)[i];
  *(float4*)ka = ((const float4*)mk)[i];
  *(float4*)va = ((const float4*)mv)[i];
  *(float4*)ra = ((const float4*)mr)[i];
  ushort4 uk, uv, ur;
  unsigned short* pk = (unsigned short*)&uk;
  unsigned short* pv = (unsigned short*)&uv;
  unsigned short* pr = (unsigned short*)&ur;
#pragma unroll
  for (int c = 0; c < 4; ++c) {
    float xn = (xa[c] - m0) * s0 * ga[c] + ba[c];
    float xp = hp ? (pa[c] - m1) * s1 * ga[c] + ba[c] : 0.f;   // shift: row 0 -> zeros
    pk[c] = f2bf(xn * ka[c] + xp * (1.f - ka[c]));
    pv[c] = f2bf(xn * va[c] + xp * (1.f - va[c]));
    pr[c] = f2bf(xn * ra[c] + xp * (1.f - ra[c]));
  }
  ((ushort4*)(ok + (size_t)row * kD))[i] = uk;
  ((ushort4*)(ov + (size_t)row * kD))[i] = uv;
  ((ushort4*)(orr + (size_t)row * kD))[i] = ur;
}

// ---------------- LN apply + shift for channel mix: ymix = 0.5(yn+yp), yn ----------------
__global__ __launch_bounds__(256) void k_ln_mix2(
    const float* __restrict__ X, const float* __restrict__ mean, const float* __restrict__ rstd,
    const float* __restrict__ g, const float* __restrict__ be,
    bf16_t* __restrict__ om, bf16_t* __restrict__ on) {
  const int row = blockIdx.x;
  const int l = row & (kL - 1);
  const int i = threadIdx.x;
  const bool hp = (l != 0);
  const float m0 = mean[row], s0 = rstd[row];
  const float m1 = hp ? mean[row - 1] : 0.f;
  const float s1 = hp ? rstd[row - 1] : 0.f;
  float xa[4], pa[4] = {0.f, 0.f, 0.f, 0.f}, ga[4], ba[4];
  *(float4*)xa = ((const float4*)(X + (size_t)row * kD))[i];
  if (hp) *(float4*)pa = ((const float4*)(X + (size_t)(row - 1) * kD))[i];
  *(float4*)ga = ((const float4*)g)[i];
  *(float4*)ba = ((const float4*)be)[i];
  ushort4 um, un;
  unsigned short* qm = (unsigned short*)&um;
  unsigned short* qn = (unsigned short*)&un;
#pragma unroll
  for (int c = 0; c < 4; ++c) {
    float yn = (xa[c] - m0) * s0 * ga[c] + ba[c];
    float yp = hp ? (pa[c] - m1) * s1 * ga[c] + ba[c] : 0.f;
    qm[c] = f2bf(0.5f * (yn + yp));
    qn[c] = f2bf(yn);
  }
  ((ushort4*)(om + (size_t)row * kD))[i] = um;
  ((ushort4*)(on + (size_t)row * kD))[i] = un;
}

// ===================== WKV: segmented parallel scan over L =====================
__global__ __launch_bounds__(256) void k_wkv_seg(
    const unsigned short* __restrict__ kq, const unsigned short* __restrict__ vq,
    const float* __restrict__ td, const float* __restrict__ tf,
    float* __restrict__ segA, float* __restrict__ segB) {
  const int d = blockIdx.x * 256 + threadIdx.x;
  const int b = blockIdx.y;
  const int s = blockIdx.z;
  const float ew = __expf(-__expf(td[d]));
  const float uu = (s == 0) ? tf[d] : 0.f;
  const size_t base = ((size_t)b * kL + (size_t)s * kP) * kD + d;
  float a = 0.f, bb = 0.f;
  unsigned short kA[16], vA[16], kB[16], vB[16];
  auto pref = [&](unsigned short* ka, unsigned short* va, int c) {
    const size_t o0 = base + (size_t)c * 16 * kD;
#pragma unroll
    for (int j = 0; j < 16; ++j) {
      ka[j] = kq[o0 + (size_t)j * kD];
      va[j] = vq[o0 + (size_t)j * kD];
    }
  };
  auto comp = [&](const unsigned short* ka, const unsigned short* va, int c) {
#pragma unroll
    for (int j = 0; j < 16; ++j) {
      float kf = bf2f(ka[j]);
      if (s == 0 && c == 0 && j == 0) kf += uu;    // t==0: exp(u + k0)
      float ek = __expf(kf);
      a = ew * a + ek * bf2f(va[j]);
      bb = ew * bb + ek;
    }
  };
  pref(kA, vA, 0);
  pref(kB, vB, 1); comp(kA, vA, 0);
  pref(kA, vA, 2); comp(kB, vB, 1);
  pref(kB, vB, 3); comp(kA, vA, 2);
  comp(kB, vB, 3);
  const size_t sidx = ((size_t)b * kSeg + s) * kD + d;
  segA[sidx] = a;
  segB[sidx] = bb;
}

__global__ __launch_bounds__(256) void k_wkv_carry(
    const float* __restrict__ td,
    const float* __restrict__ segA, const float* __restrict__ segB,
    float* __restrict__ carA, float* __restrict__ carB) {
  const int d = blockIdx.x * 256 + threadIdx.x;
  const int b = blockIdx.y;
  const float ew = __expf(-__expf(td[d]));
  float ewP = ew;
#pragma unroll
  for (int i = 0; i < 6; ++i) ewP *= ewP;          // ew^64
  float ca = 0.f, cb = 0.f;
#pragma unroll 4
  for (int s = 0; s < kSeg; ++s) {
    const size_t idx = ((size_t)b * kSeg + s) * kD + d;
    carA[idx] = ca;
    carB[idx] = cb;
    ca = ewP * ca + segA[idx];
    cb = ewP * cb + segB[idx];
  }
}

__global__ __launch_bounds__(256) void k_wkv_out(
    const unsigned short* __restrict__ kq, const unsigned short* __restrict__ vq,
    const unsigned short* __restrict__ rq, const float* __restrict__ td,
    const float* __restrict__ tf, const float* __restrict__ carA,
    const float* __restrict__ carB, unsigned short* __restrict__ out) {
  const int d = blockIdx.x * 256 + threadIdx.x;
  const int b = blockIdx.y;
  const int s = blockIdx.z;
  const float ew = __expf(-__expf(td[d]));
  const float uu = (s == 0) ? tf[d] : 0.f;
  const size_t base = ((size_t)b * kL + (size_t)s * kP) * kD + d;
  const size_t sidx = ((size_t)b * kSeg + s) * kD + d;
  float a = carA[sidx], bb = carB[sidx];
  unsigned short kA[16], vA[16], rA[16], kB[16], vB[16], rB[16];
  auto pref = [&](unsigned short* ka, unsigned short* va, unsigned short* ra, int c) {
    const size_t o0 = base + (size_t)c * 16 * kD;
#pragma unroll
    for (int j = 0; j < 16; ++j) {
      ka[j] = kq[o0 + (size_t)j * kD];
      va[j] = vq[o0 + (size_t)j * kD];
      ra[j] = rq[o0 + (size_t)j * kD];
    }
  };
  auto comp = [&](const unsigned short* ka, const unsigned short* va,
                  const unsigned short* ra, int c) {
    const size_t o0 = base + (size_t)c * 16 * kD;
#pragma unroll
    for (int j = 0; j < 16; ++j) {
      float kf = bf2f(ka[j]);
      if (s == 0 && c == 0 && j == 0) kf += uu;
      float ek = __expf(kf);
      a = ew * a + ek * bf2f(va[j]);
      bb = ew * bb + ek;
      float y = a / (bb + 1e-8f);
      float sr = 1.f / (1.f + __expf(-bf2f(ra[j])));
      out[o0 + (size_t)j * kD] = f2bf(sr * y);
    }
  };
  pref(kA, vA, rA, 0);
  pref(kB, vB, rB, 1); comp(kA, vA, rA, 0);
  pref(kA, vA, rA, 2); comp(kB, vB, rB, 1);
  pref(kB, vB, rB, 3); comp(kA, vA, rA, 2);
  comp(kB, vB, rB, 3);
}

// ====== bf16 MFMA GEMM: BM=BN=256 BK=64, 8 waves of 128x64, m201 8-phase ======
// Per K-tile: 4 phases {reads -> barrier -> lgkm(0)+sched_barrier -> 16 MFMA -> barrier},
// quadrants (ks,mh). Staging split in half-tiles: P0(t) stages HI(t+1) into the
// other buffer (tile t-1 dead); P3(t) stages LO(t+2) into current buffer's dead
// quarters (A rows 0-63/128-191 + B rows 0-127, all last read at P2). Counted
// vmcnt(4) once per tile at the boundary: only the 4 LO(t+2) ops stay in flight.
// T1 XCD bands, T2 XOR swizzle (pre-swizzled src + swizzled reads), T5 setprio.
template <int EPI>
__global__ __launch_bounds__(512, 2) void gemmT(
    const bf16_t* __restrict__ A0, long strA, int lda,
    const bf16_t* __restrict__ B0, long strB, int ldb,
    bf16_t* __restrict__ Cb0, float* __restrict__ Cf, long strC,
    int N, int K, int nbx,
    const float* __restrict__ addf, const bf16_t* __restrict__ mulb) {
  __shared__ __align__(16) char lds[131072];   // 2 x (A[256][64]bf16 @0 + B[256][64] @32768)
  const int z = blockIdx.z;
  const bf16_t* A = A0 + (size_t)z * strA;
  const bf16_t* Bt = B0 + (size_t)z * strB;
  const int nwg = gridDim.x;
  const int wg = (blockIdx.x & 7) * (nwg >> 3) + (blockIdx.x >> 3);
  const int by = wg / nbx, bx = wg - by * nbx;
  const long brow = (long)by * 256;
  const long bcol = (long)bx * 256;
  const int tid = threadIdx.x;
  const int lane = tid & 63;
  const int wid = tid >> 6;
  const int wr = wid >> 2, wc = wid & 3;   // 2 x 4 waves, each owns 128x64 out

  f32x4 acc[8][4] = {};

  // staging sources: thread covers 16B at (row = q*64 + tid>>3, slot=(tid&7)*16),
  // pre-swizzled source col (rule #21)
  const int trow = tid >> 3;
  const int scol = ((tid & 7) * 16) ^ ((trow & 7) << 4);
  const char* Ag = (const char*)(A + (brow + trow) * (size_t)lda) + scol;
  const char* Bg = (const char*)(Bt + (bcol + trow) * (size_t)ldb) + scol;
  const long rsA = 64L * lda * 2;
  const long rsB = 64L * ldb * 2;

  // each gld16 line covers 8 KB = 64 rows x 128B (all 8 waves)
#define STG_FULL(kt, db) { const long kb = (long)(kt) * 128;       \
    gld16(Ag + kb,           (db) + tid * 16);                     \
    gld16(Ag + kb + rsA,     (db) + 8192 + tid * 16);              \
    gld16(Ag + kb + 2 * rsA, (db) + 16384 + tid * 16);             \
    gld16(Ag + kb + 3 * rsA, (db) + 24576 + tid * 16);             \
    gld16(Bg + kb,           (db) + 32768 + tid * 16);             \
    gld16(Bg + kb + rsB,     (db) + 40960 + tid * 16);             \
    gld16(Bg + kb + 2 * rsB, (db) + 49152 + tid * 16);             \
    gld16(Bg + kb + 3 * rsB, (db) + 57344 + tid * 16); }
#define STG_HI(kt, db) { const long kb = (long)(kt) * 128;         \
    gld16(Ag + kb + rsA,     (db) + 8192 + tid * 16);              \
    gld16(Ag + kb + 3 * rsA, (db) + 24576 + tid * 16);             \
    gld16(Bg + kb + 2 * rsB, (db) + 49152 + tid * 16);             \
    gld16(Bg + kb + 3 * rsB, (db) + 57344 + tid * 16); }
#define STG_LO(kt, db) { const long kb = (long)(kt) * 128;         \
    gld16(Ag + kb,           (db) + tid * 16);                     \
    gld16(Ag + kb + 2 * rsA, (db) + 16384 + tid * 16);             \
    gld16(Bg + kb,           (db) + 32768 + tid * 16);             \
    gld16(Bg + kb + rsB,     (db) + 40960 + tid * 16); }

  // fragment reads (swizzled): row r, logical byte-col c -> c ^ ((r&7)<<4)
  const int l16 = lane & 15, kq = lane >> 4;
  const int swz = (l16 & 7) << 4;
  const int oS0 = (kq * 16) ^ swz;          // k-slice 0 (k 0..31)
  const int oS1 = (64 + kq * 16) ^ swz;     // k-slice 1 (k 32..63)
  const int ArowB = (wr * 128 + l16) * 128;
  const int BrowB = 32768 + (wc * 64 + l16) * 128;

  bf16x8 aF[4], aG[4], bF[4];
  const int NT = K >> 6;

  // prologue: tile0 full + tile1 LO half; allow the 4 LO ops in flight
  STG_FULL(0, lds)
  if (NT > 1) {
    STG_LO(1, lds + 65536)
    asm volatile("s_waitcnt vmcnt(4)" ::: "memory");
  } else {
    asm volatile("s_waitcnt vmcnt(0)" ::: "memory");
  }
  __builtin_amdgcn_s_barrier();

#define PH_TAIL                                            \
  __builtin_amdgcn_s_barrier();                            \
  asm volatile("s_waitcnt lgkmcnt(0)" ::: "memory");       \
  __builtin_amdgcn_sched_barrier(0);                       \
  __builtin_amdgcn_s_setprio(1);

#define MFMA16(AR, MB)                                     \
  _Pragma("unroll")                                        \
  for (int i = 0; i < 4; ++i)                              \
    _Pragma("unroll")                                      \
    for (int n = 0; n < 4; ++n)                            \
      acc[(MB) + i][n] = __builtin_amdgcn_mfma_f32_16x16x32_bf16(AR[i], bF[n], acc[(MB) + i][n], 0, 0, 0);

  for (int t = 0; t < NT; ++t) {
    const char* bc = lds + (t & 1) * 65536;
    char* bn = lds + ((t + 1) & 1) * 65536;
    char* bw = lds + (t & 1) * 65536;
    // ---- P0: (ks0, mh0) + B ks0; stage HI(t+1) -> other buffer ----
#pragma unroll
    for (int i = 0; i < 4; ++i) aF[i] = *(const bf16x8*)(bc + ArowB + i * 2048 + oS0);
#pragma unroll
    for (int n = 0; n < 4; ++n) bF[n] = *(const bf16x8*)(bc + BrowB + n * 2048 + oS0);
    if (t + 1 < NT) STG_HI(t + 1, bn)
    PH_TAIL
    MFMA16(aF, 0)
    __builtin_amdgcn_s_setprio(0);
    __builtin_amdgcn_s_barrier();
    // ---- P1: (ks0, mh1) ----
#pragma unroll
    for (int i = 0; i < 4; ++i) aG[i] = *(const bf16x8*)(bc + ArowB + 8192 + i * 2048 + oS0);
    PH_TAIL
    MFMA16(aG, 4)
    __builtin_amdgcn_s_setprio(0);
    __builtin_amdgcn_s_barrier();
    // ---- P2: (ks1, mh0) + B ks1 ----
#pragma unroll
    for (int i = 0; i < 4; ++i) aF[i] = *(const bf16x8*)(bc + ArowB + i * 2048 + oS1);
#pragma unroll
    for (int n = 0; n < 4; ++n) bF[n] = *(const bf16x8*)(bc + BrowB + n * 2048 + oS1);
    PH_TAIL
    MFMA16(aF, 0)
    __builtin_amdgcn_s_setprio(0);
    __builtin_amdgcn_s_barrier();
    // ---- P3: (ks1, mh1); stage LO(t+2) -> current buffer's dead quarters ----
#pragma unroll
    for (int i = 0; i < 4; ++i) aG[i] = *(const bf16x8*)(bc + ArowB + 8192 + i * 2048 + oS1);
    if (t + 2 < NT) STG_LO(t + 2, bw)
    PH_TAIL
    MFMA16(aG, 4)
    __builtin_amdgcn_s_setprio(0);
    // tile boundary: force tile t+1 staged (allow LO(t+2)'s 4 ops in flight)
    if (t + 2 < NT) { asm volatile("s_waitcnt vmcnt(4)" ::: "memory"); }
    else            { asm volatile("s_waitcnt vmcnt(0)" ::: "memory"); }
    __builtin_amdgcn_s_barrier();
  }
#undef STG_FULL
#undef STG_HI
#undef STG_LO
#undef PH_TAIL
#undef MFMA16

  bf16_t* Cb = Cb0 + (size_t)z * strC;
  const long orow = brow + wr * 128 + (lane >> 4) * 4;  // C/D: col=lane&15, row=(lane>>4)*4+reg
  const long ocol = bcol + wc * 64 + l16;
#pragma unroll
  for (int m = 0; m < 8; ++m) {
#pragma unroll
    for (int reg = 0; reg < 4; ++reg) {
      const long r = orow + m * 16 + reg;
#pragma unroll
      for (int n = 0; n < 4; ++n) {
        const size_t idx = (size_t)r * N + ocol + n * 16;
        const float v = acc[m][n][reg];
        if constexpr (EPI == 0) {
          Cb[idx] = __float2bfloat16(v);
        } else if constexpr (EPI == 1) {
          Cf[idx] = addf[idx] + v;
        } else if constexpr (EPI == 2) {
          float u = v > 0.f ? v : 0.f;
          Cb[idx] = __float2bfloat16(u * u);
        } else if constexpr (EPI == 3) {
          Cb[idx] = __float2bfloat16(1.f / (1.f + __expf(-v)));
        } else if constexpr (EPI == 4) {
          Cf[idx] = v;
        } else {
          Cf[idx] = addf[idx] + __bfloat162float(mulb[idx]) * (Cf[idx] + v);
        }
      }
    }
  }
}

extern "C" void kernel_launch(void* const* d_in, const int* in_sizes, int n_in,
                              void* d_out, int out_size, void* d_ws, size_t ws_size,
                              hipStream_t stream) {
  const float* x    = (const float*)d_in[0];
  const float* ln1g = (const float*)d_in[1];
  const float* ln1b = (const float*)d_in[2];
  const float* Wk   = (const float*)d_in[3];
  const float* Wv   = (const float*)d_in[4];
  const float* Wr   = (const float*)d_in[5];
  const float* Wo   = (const float*)d_in[6];
  const float* td   = (const float*)d_in[7];
  const float* tf   = (const float*)d_in[8];
  const float* mk   = (const float*)d_in[9];
  const float* mv   = (const float*)d_in[10];
  const float* mr   = (const float*)d_in[11];
  const float* ln2g = (const float*)d_in[12];
  const float* ln2b = (const float*)d_in[13];
  const float* Wfk  = (const float*)d_in[14];
  const float* Wfv  = (const float*)d_in[15];
  const float* Wfr  = (const float*)d_in[16];

  char* ws = (char*)d_ws;
  const size_t MB = 1ull << 20;
  bf16_t* WkT  = (bf16_t*)(ws + 0 * MB);
  bf16_t* WvT  = (bf16_t*)(ws + 2 * MB);
  bf16_t* WrT  = (bf16_t*)(ws + 4 * MB);
  bf16_t* WoT  = (bf16_t*)(ws + 6 * MB);
  bf16_t* WfkT = (bf16_t*)(ws + 8 * MB);    // [4096][1024]
  bf16_t* WfvT = (bf16_t*)(ws + 16 * MB);   // [1024][4096]
  bf16_t* WfrT = (bf16_t*)(ws + 24 * MB);
  float* mean1 = (float*)(ws + 26 * MB);
  float* rstd1 = (float*)(ws + 26 * MB + 65536);
  float* mean2 = (float*)(ws + 26 * MB + 131072);
  float* rstd2 = (float*)(ws + 26 * MB + 196608);
  bf16_t* xk   = (bf16_t*)(ws + 28 * MB);
  bf16_t* xv   = (bf16_t*)(ws + 60 * MB);
  bf16_t* xr   = (bf16_t*)(ws + 92 * MB);
  bf16_t* kbuf = (bf16_t*)(ws + 124 * MB);
  bf16_t* vbuf = (bf16_t*)(ws + 156 * MB);
  bf16_t* rbuf = (bf16_t*)(ws + 188 * MB);
  float*  segA = (float*)(ws + 60 * MB);
  float*  segB = (float*)(ws + 61 * MB);
  float*  carA = (float*)(ws + 62 * MB);
  float*  carB = (float*)(ws + 63 * MB);
  bf16_t* rwkv = (bf16_t*)(ws + 92 * MB);
  float*  x1   = (float*)(ws + 28 * MB);    // f32 64 MB
  bf16_t* rr   = (bf16_t*)(ws + 92 * MB);
  bf16_t* ynb  = (bf16_t*)(ws + 124 * MB);
  bf16_t* kk   = (bf16_t*)(ws + 124 * MB);  // [16384][2048] bf16 = 64 MB
  bf16_t* ymix = (bf16_t*)(ws + 188 * MB);
  float*  out  = (float*)d_out;
  const long sX = (long)kM * kD;            // 16777216 elems
  const long sW = (long)kD * kD;            // 1048576 elems

  dim3 blk(256), blkg(512);
  // weights -> bf16 B^T
  k_transpose_cast<<<dim3(32, 32), blk, 0, stream>>>(Wk, WkT, 1024, 1024);
  k_transpose_cast<<<dim3(32, 32), blk, 0, stream>>>(Wv, WvT, 1024, 1024);
  k_transpose_cast<<<dim3(32, 32), blk, 0, stream>>>(Wr, WrT, 1024, 1024);
  k_transpose_cast<<<dim3(32, 32), blk, 0, stream>>>(Wo, WoT, 1024, 1024);
  k_transpose_cast<<<dim3(128, 32), blk, 0, stream>>>(Wfk, WfkT, 1024, 4096);
  k_transpose_cast<<<dim3(32, 128), blk, 0, stream>>>(Wfv, WfvT, 4096, 1024);
  k_transpose_cast<<<dim3(32, 32), blk, 0, stream>>>(Wfr, WfrT, 1024, 1024);

  // ---- time mixing ----
  k_ln_stats<<<kM / 4, blk, 0, stream>>>(x, mean1, rstd1);
  k_ln_mix1<<<kM, blk, 0, stream>>>(x, mean1, rstd1, ln1g, ln1b, mk, mv, mr, xk, xv, xr);
  gemmT<0><<<dim3(256, 1, 3), blkg, 0, stream>>>(xk, sX, 1024, WkT, sW, 1024,
      kbuf, nullptr, sX, 1024, 1024, 4, nullptr, nullptr);
  k_wkv_seg<<<dim3(4, 8, kSeg), blk, 0, stream>>>((const unsigned short*)kbuf,
      (const unsigned short*)vbuf, td, tf, segA, segB);
  k_wkv_carry<<<dim3(4, 8), blk, 0, stream>>>(td, segA, segB, carA, carB);
  k_wkv_out<<<dim3(4, 8, kSeg), blk, 0, stream>>>((const unsigned short*)kbuf,
      (const unsigned short*)vbuf, (const unsigned short*)rbuf, td, tf, carA, carB,
      (unsigned short*)rwkv);
  gemmT<1><<<256, blkg, 0, stream>>>(rwkv, 0, 1024, WoT, 0, 1024,
      nullptr, x1, 0, 1024, 1024, 4, x, nullptr);

  // ---- channel mixing ----
  k_ln_stats<<<kM / 4, blk, 0, stream>>>(x1, mean2, rstd2);
  k_ln_mix2<<<kM, blk, 0, stream>>>(x1, mean2, rstd2, ln2g, ln2b, ymix, ynb);
  gemmT<3><<<256, blkg, 0, stream>>>(ynb, 0, 1024, WfrT, 0, 1024,
      rr, nullptr, 0, 1024, 1024, 4, nullptr, nullptr);
  // hidden dim in 2 chunks of 2048: kk = relu(ymix@Wfk[:,c])^2; out (+)= kk@Wfv[c,:]
  for (int c = 0; c < 2; ++c) {
    gemmT<2><<<512, blkg, 0, stream>>>(ymix, 0, 1024, WfkT + (size_t)c * 2048 * 1024, 0, 1024,
        kk, nullptr, 0, 2048, 1024, 8, nullptr, nullptr);
    if (c == 0)
      gemmT<4><<<256, blkg, 0, stream>>>(kk, 0, 2048, WfvT + 0, 0, 4096,
          nullptr, out, 0, 1024, 2048, 4, nullptr, nullptr);
    else
      gemmT<6><<<256, blkg, 0, stream>>>(kk, 0, 2048, WfvT + 2048, 0, 4096,
          nullptr, out, 0, 1024, 2048, 4, x1, rr);
  }
}

// Round 8
// 642.130 us; speedup vs baseline: 1.0528x; 1.0528x over previous
//
#include <hip/hip_runtime.h>
#include <hip/hip_bf16.h>
#include <stdint.h>

typedef __hip_bfloat16 bf16_t;
typedef __attribute__((ext_vector_type(8))) short bf16x8;   // 8 bf16 = 4 VGPR
typedef __attribute__((ext_vector_type(4))) float f32x4;

#define DEV static __device__ __forceinline__

constexpr int kBB = 8, kL = 2048, kD = 1024;
constexpr int kM = kBB * kL;   // 16384 rows
constexpr int kSeg = 32, kP = 64;   // WKV: 32 segments x 64 steps

DEV float bf2f(unsigned short u) { return __uint_as_float((unsigned)u << 16); }
DEV unsigned short f2bf(float f) {
  unsigned u = __float_as_uint(f);
  return (unsigned short)((u + 0x7fffu + ((u >> 16) & 1u)) >> 16);  // RNE
}

// async global->LDS, 16B per lane. LDS dest is wave-uniform-base + lane*16.
DEV void gld16(const void* g, void* l) {
  const __attribute__((address_space(1))) unsigned* gp =
      (const __attribute__((address_space(1))) unsigned*)(uintptr_t)g;
  __attribute__((address_space(3))) unsigned* lp =
      (__attribute__((address_space(3))) unsigned*)(unsigned)(uintptr_t)l;
  __builtin_amdgcn_global_load_lds(gp, lp, 16, 0, 0);
}

// ---------------- weight transpose + cast: W[R][C] f32 -> Wt[C][R] bf16 ---------------
__global__ __launch_bounds__(256) void k_transpose_cast(
    const float* __restrict__ W, bf16_t* __restrict__ Wt, int R, int C) {
  __shared__ float tile[32][33];
  const int bx = blockIdx.x * 32;           // C-dim base
  const int by = blockIdx.y * 32;           // R-dim base
  const int tx = threadIdx.x & 31, ty = threadIdx.x >> 5;  // 32 x 8
#pragma unroll
  for (int i = 0; i < 32; i += 8)
    tile[ty + i][tx] = W[(size_t)(by + ty + i) * C + (bx + tx)];
  __syncthreads();
#pragma unroll
  for (int i = 0; i < 32; i += 8)
    Wt[(size_t)(bx + ty + i) * R + (by + tx)] = __float2bfloat16(tile[tx][ty + i]);
}

// -------- fused LN(+stats)+shift+time-mix -> xk/xv/xr (bf16); one block per row --------
__global__ __launch_bounds__(256) void k_ln1f(
    const float* __restrict__ X, const float* __restrict__ g, const float* __restrict__ be,
    const float* __restrict__ mk, const float* __restrict__ mv, const float* __restrict__ mr,
    bf16_t* __restrict__ ok, bf16_t* __restrict__ ov, bf16_t* __restrict__ orr) {
  const int row = blockIdx.x;
  const int l = row & (kL - 1);
  const int i = threadIdx.x;                 // 4 floats per thread
  const bool hp = (l != 0);
  float xa[4], pa[4] = {0.f, 0.f, 0.f, 0.f};
  *(float4*)xa = ((const float4*)(X + (size_t)row * kD))[i];
  if (hp) *(float4*)pa = ((const float4*)(X + (size_t)(row - 1) * kD))[i];
  float s0 = xa[0] + xa[1] + xa[2] + xa[3];
  float q0 = xa[0] * xa[0] + xa[1] * xa[1] + xa[2] * xa[2] + xa[3] * xa[3];
  float s1 = pa[0] + pa[1] + pa[2] + pa[3];
  float q1 = pa[0] * pa[0] + pa[1] * pa[1] + pa[2] * pa[2] + pa[3] * pa[3];
#pragma unroll
  for (int off = 32; off > 0; off >>= 1) {
    s0 += __shfl_xor(s0, off); q0 += __shfl_xor(q0, off);
    s1 += __shfl_xor(s1, off); q1 += __shfl_xor(q1, off);
  }
  __shared__ float red[4][4];
  const int wid = i >> 6, lane = i & 63;
  if (lane == 0) { red[wid][0] = s0; red[wid][1] = q0; red[wid][2] = s1; red[wid][3] = q1; }
  __syncthreads();
  s0 = red[0][0] + red[1][0] + red[2][0] + red[3][0];
  q0 = red[0][1] + red[1][1] + red[2][1] + red[3][1];
  s1 = red[0][2] + red[1][2] + red[2][2] + red[3][2];
  q1 = red[0][3] + red[1][3] + red[2][3] + red[3][3];
  const float m0 = s0 * (1.f / kD);
  const float r0 = rsqrtf(fmaxf(q0 * (1.f / kD) - m0 * m0, 0.f) + 1e-5f);
  const float m1 = s1 * (1.f / kD);
  const float r1 = rsqrtf(fmaxf(q1 * (1.f / kD) - m1 * m1, 0.f) + 1e-5f);
  float ga[4], ba[4], ka[4], va[4], ra[4];
  *(float4*)ga = ((const float4*)g)[i];
  *(float4*)ba = ((const float4*)be)[i];
  *(float4*)ka = ((const float4*)mk)[i];
  *(float4*)va = ((const float4*)mv)[i];
  *(float4*)ra = ((const float4*)mr)[i];
  ushort4 uk, uv, ur;
  unsigned short* pk = (unsigned short*)&uk;
  unsigned short* pv = (unsigned short*)&uv;
  unsigned short* pr = (unsigned short*)&ur;
#pragma unroll
  for (int c = 0; c < 4; ++c) {
    float xn = (xa[c] - m0) * r0 * ga[c] + ba[c];
    float xp = hp ? (pa[c] - m1) * r1 * ga[c] + ba[c] : 0.f;   // shift: row 0 -> zeros
    pk[c] = f2bf(xn * ka[c] + xp * (1.f - ka[c]));
    pv[c] = f2bf(xn * va[c] + xp * (1.f - va[c]));
    pr[c] = f2bf(xn * ra[c] + xp * (1.f - ra[c]));
  }
  ((ushort4*)(ok + (size_t)row * kD))[i] = uk;
  ((ushort4*)(ov + (size_t)row * kD))[i] = uv;
  ((ushort4*)(orr + (size_t)row * kD))[i] = ur;
}

// -------- fused LN(+stats)+shift for channel mix: ymix = 0.5(yn+yp), ynb = yn --------
__global__ __launch_bounds__(256) void k_ln2f(
    const float* __restrict__ X, const float* __restrict__ g, const float* __restrict__ be,
    bf16_t* __restrict__ om, bf16_t* __restrict__ on) {
  const int row = blockIdx.x;
  const int l = row & (kL - 1);
  const int i = threadIdx.x;
  const bool hp = (l != 0);
  float xa[4], pa[4] = {0.f, 0.f, 0.f, 0.f};
  *(float4*)xa = ((const float4*)(X + (size_t)row * kD))[i];
  if (hp) *(float4*)pa = ((const float4*)(X + (size_t)(row - 1) * kD))[i];
  float s0 = xa[0] + xa[1] + xa[2] + xa[3];
  float q0 = xa[0] * xa[0] + xa[1] * xa[1] + xa[2] * xa[2] + xa[3] * xa[3];
  float s1 = pa[0] + pa[1] + pa[2] + pa[3];
  float q1 = pa[0] * pa[0] + pa[1] * pa[1] + pa[2] * pa[2] + pa[3] * pa[3];
#pragma unroll
  for (int off = 32; off > 0; off >>= 1) {
    s0 += __shfl_xor(s0, off); q0 += __shfl_xor(q0, off);
    s1 += __shfl_xor(s1, off); q1 += __shfl_xor(q1, off);
  }
  __shared__ float red[4][4];
  const int wid = i >> 6, lane = i & 63;
  if (lane == 0) { red[wid][0] = s0; red[wid][1] = q0; red[wid][2] = s1; red[wid][3] = q1; }
  __syncthreads();
  s0 = red[0][0] + red[1][0] + red[2][0] + red[3][0];
  q0 = red[0][1] + red[1][1] + red[2][1] + red[3][1];
  s1 = red[0][2] + red[1][2] + red[2][2] + red[3][2];
  q1 = red[0][3] + red[1][3] + red[2][3] + red[3][3];
  const float m0 = s0 * (1.f / kD);
  const float r0 = rsqrtf(fmaxf(q0 * (1.f / kD) - m0 * m0, 0.f) + 1e-5f);
  const float m1 = s1 * (1.f / kD);
  const float r1 = rsqrtf(fmaxf(q1 * (1.f / kD) - m1 * m1, 0.f) + 1e-5f);
  float ga[4], ba[4];
  *(float4*)ga = ((const float4*)g)[i];
  *(float4*)ba = ((const float4*)be)[i];
  ushort4 um, un;
  unsigned short* qm = (unsigned short*)&um;
  unsigned short* qn = (unsigned short*)&un;
#pragma unroll
  for (int c = 0; c < 4; ++c) {
    float yn = (xa[c] - m0) * r0 * ga[c] + ba[c];
    float yp = hp ? (pa[c] - m1) * r1 * ga[c] + ba[c] : 0.f;
    qm[c] = f2bf(0.5f * (yn + yp));
    qn[c] = f2bf(yn);
  }
  ((ushort4*)(om + (size_t)row * kD))[i] = um;
  ((ushort4*)(on + (size_t)row * kD))[i] = un;
}

// ===================== WKV: segmented parallel scan over L =====================
__global__ __launch_bounds__(256) void k_wkv_seg(
    const unsigned short* __restrict__ kq, const unsigned short* __restrict__ vq,
    const float* __restrict__ td, const float* __restrict__ tf,
    float* __restrict__ segA, float* __restrict__ segB) {
  const int d = blockIdx.x * 256 + threadIdx.x;
  const int b = blockIdx.y;
  const int s = blockIdx.z;
  const float ew = __expf(-__expf(td[d]));
  const float uu = (s == 0) ? tf[d] : 0.f;
  const size_t base = ((size_t)b * kL + (size_t)s * kP) * kD + d;
  float a = 0.f, bb = 0.f;
  unsigned short kA[16], vA[16], kB[16], vB[16];
  auto pref = [&](unsigned short* ka, unsigned short* va, int c) {
    const size_t o0 = base + (size_t)c * 16 * kD;
#pragma unroll
    for (int j = 0; j < 16; ++j) {
      ka[j] = kq[o0 + (size_t)j * kD];
      va[j] = vq[o0 + (size_t)j * kD];
    }
  };
  auto comp = [&](const unsigned short* ka, const unsigned short* va, int c) {
#pragma unroll
    for (int j = 0; j < 16; ++j) {
      float kf = bf2f(ka[j]);
      if (s == 0 && c == 0 && j == 0) kf += uu;    // t==0: exp(u + k0)
      float ek = __expf(kf);
      a = ew * a + ek * bf2f(va[j]);
      bb = ew * bb + ek;
    }
  };
  pref(kA, vA, 0);
  pref(kB, vB, 1); comp(kA, vA, 0);
  pref(kA, vA, 2); comp(kB, vB, 1);
  pref(kB, vB, 3); comp(kA, vA, 2);
  comp(kB, vB, 3);
  const size_t sidx = ((size_t)b * kSeg + s) * kD + d;
  segA[sidx] = a;
  segB[sidx] = bb;
}

__global__ __launch_bounds__(256) void k_wkv_carry(
    const float* __restrict__ td,
    const float* __restrict__ segA, const float* __restrict__ segB,
    float* __restrict__ carA, float* __restrict__ carB) {
  const int d = blockIdx.x * 256 + threadIdx.x;
  const int b = blockIdx.y;
  const float ew = __expf(-__expf(td[d]));
  float ewP = ew;
#pragma unroll
  for (int i = 0; i < 6; ++i) ewP *= ewP;          // ew^64
  float ca = 0.f, cb = 0.f;
#pragma unroll 4
  for (int s = 0; s < kSeg; ++s) {
    const size_t idx = ((size_t)b * kSeg + s) * kD + d;
    carA[idx] = ca;
    carB[idx] = cb;
    ca = ewP * ca + segA[idx];
    cb = ewP * cb + segB[idx];
  }
}

__global__ __launch_bounds__(256) void k_wkv_out(
    const unsigned short* __restrict__ kq, const unsigned short* __restrict__ vq,
    const unsigned short* __restrict__ rq, const float* __restrict__ td,
    const float* __restrict__ tf, const float* __restrict__ carA,
    const float* __restrict__ carB, unsigned short* __restrict__ out) {
  const int d = blockIdx.x * 256 + threadIdx.x;
  const int b = blockIdx.y;
  const int s = blockIdx.z;
  const float ew = __expf(-__expf(td[d]));
  const float uu = (s == 0) ? tf[d] : 0.f;
  const size_t base = ((size_t)b * kL + (size_t)s * kP) * kD + d;
  const size_t sidx = ((size_t)b * kSeg + s) * kD + d;
  float a = carA[sidx], bb = carB[sidx];
  unsigned short kA[16], vA[16], rA[16], kB[16], vB[16], rB[16];
  auto pref = [&](unsigned short* ka, unsigned short* va, unsigned short* ra, int c) {
    const size_t o0 = base + (size_t)c * 16 * kD;
#pragma unroll
    for (int j = 0; j < 16; ++j) {
      ka[j] = kq[o0 + (size_t)j * kD];
      va[j] = vq[o0 + (size_t)j * kD];
      ra[j] = rq[o0 + (size_t)j * kD];
    }
  };
  auto comp = [&](const unsigned short* ka, const unsigned short* va,
                  const unsigned short* ra, int c) {
    const size_t o0 = base + (size_t)c * 16 * kD;
#pragma unroll
    for (int j = 0; j < 16; ++j) {
      float kf = bf2f(ka[j]);
      if (s == 0 && c == 0 && j == 0) kf += uu;
      float ek = __expf(kf);
      a = ew * a + ek * bf2f(va[j]);
      bb = ew * bb + ek;
      float y = a / (bb + 1e-8f);
      float sr = 1.f / (1.f + __expf(-bf2f(ra[j])));
      out[o0 + (size_t)j * kD] = f2bf(sr * y);
    }
  };
  pref(kA, vA, rA, 0);
  pref(kB, vB, rB, 1); comp(kA, vA, rA, 0);
  pref(kA, vA, rA, 2); comp(kB, vB, rB, 1);
  pref(kB, vB, rB, 3); comp(kA, vA, rA, 2);
  comp(kB, vB, rB, 3);
}

// ====== bf16 MFMA GEMM: BM=BN=256 BK=64, 8 waves of 128x64, R6 skeleton + issue pins ======
// Within-wave software pipeline: each MFMA cluster consumes REGISTERS loaded one
// half-tile earlier; the 12 ds_reads for the NEXT cluster are issued right before
// the current cluster and drain under it. sched_barrier(0) pins the ISSUE ORDER
// (compiler otherwise sinks the independent reads below the MFMA burst -> pipes
// serialize; R6 measured 5260 cyc/tile = LDS 3000 + MFMA 2060 serial).
// T1 XCD bands, T2 XOR swizzle (pre-swizzled global src + swizzled reads),
// T4 one barrier/tile with vmcnt draining loads issued a full tile earlier, T5 setprio.
template <int EPI>
__global__ __launch_bounds__(512, 2) void gemmT(
    const bf16_t* __restrict__ A0, long strA, int lda,
    const bf16_t* __restrict__ B0, long strB, int ldb,
    bf16_t* __restrict__ Cb0, float* __restrict__ Cf, long strC,
    int N, int K, int nbx,
    const float* __restrict__ addf, const bf16_t* __restrict__ mulb) {
  __shared__ __align__(16) char lds[131072];   // 2 x (A[256][64]bf16 @0 + B[256][64] @32768)
  const int z = blockIdx.z;
  const bf16_t* A = A0 + (size_t)z * strA;
  const bf16_t* Bt = B0 + (size_t)z * strB;
  const int nwg = gridDim.x;
  const int wg = (blockIdx.x & 7) * (nwg >> 3) + (blockIdx.x >> 3);
  const int by = wg / nbx, bx = wg - by * nbx;
  const long brow = (long)by * 256;
  const long bcol = (long)bx * 256;
  const int tid = threadIdx.x;
  const int lane = tid & 63;
  const int wid = tid >> 6;
  const int wr = wid >> 2, wc = wid & 3;   // 2 x 4 waves, each owns 128x64 out

  f32x4 acc[8][4] = {};

  // staging: thread covers 16B at (row = q*64 + tid>>3, slot = (tid&7)*16)
  const int trow = tid >> 3;
  const int scol = ((tid & 7) * 16) ^ ((trow & 7) << 4);   // pre-swizzled source col
  const char* Ag = (const char*)(A + (brow + trow) * (size_t)lda) + scol;
  const char* Bg = (const char*)(Bt + (bcol + trow) * (size_t)ldb) + scol;
  const long rsA = 64L * lda * 2;
  const long rsB = 64L * ldb * 2;

#define STAGE(kt, p)                                   \
  {                                                    \
    const long kb = (long)(kt) * 128;                  \
    char* Ld = lds + (p) * 65536 + tid * 16;           \
    gld16(Ag + kb, Ld);                                \
    gld16(Ag + kb + rsA, Ld + 8192);                   \
    gld16(Ag + kb + 2 * rsA, Ld + 16384);              \
    gld16(Ag + kb + 3 * rsA, Ld + 24576);              \
    gld16(Bg + kb, Ld + 32768);                        \
    gld16(Bg + kb + rsB, Ld + 40960);                  \
    gld16(Bg + kb + 2 * rsB, Ld + 49152);              \
    gld16(Bg + kb + 3 * rsB, Ld + 57344);              \
  }

  // fragment reads (swizzled): row r, logical byte-col c -> c ^ ((r&7)<<4)
  const int l16 = lane & 15, kq = lane >> 4;
  const int swz = (l16 & 7) << 4;
  const int oS0 = (kq * 16) ^ swz;          // K-slice 0 (k 0..31)
  const int oS1 = (64 + kq * 16) ^ swz;     // K-slice 1 (k 32..63)
  const char* Arow = lds + (wr * 128 + l16) * 128;           // A frag m: +m*2048
  const char* Brow = lds + 32768 + (wc * 64 + l16) * 128;    // B frag n: +n*2048

  bf16x8 aE[8], bE[4], aO[8], bO[4];
  const int NT = K >> 6;

  STAGE(0, 0) STAGE(1, 1)
  asm volatile("s_waitcnt vmcnt(8)" ::: "memory");   // STAGE(0) landed
  __builtin_amdgcn_s_barrier();
#pragma unroll
  for (int m = 0; m < 8; ++m) aE[m] = *(const bf16x8*)(Arow + m * 2048 + oS0);
#pragma unroll
  for (int n = 0; n < 4; ++n) bE[n] = *(const bf16x8*)(Brow + n * 2048 + oS0);

  for (int t = 0; t < NT; ++t) {
    const int p = t & 1;
    const char* Ap = Arow + p * 65536;
    const char* Bp = Brow + p * 65536;
    // issue reads of slice1 (consumed by the NEXT cluster); pin them above MFMA
#pragma unroll
    for (int m = 0; m < 8; ++m) aO[m] = *(const bf16x8*)(Ap + m * 2048 + oS1);
#pragma unroll
    for (int n = 0; n < 4; ++n) bO[n] = *(const bf16x8*)(Bp + n * 2048 + oS1);
    __builtin_amdgcn_sched_barrier(0);
    __builtin_amdgcn_s_setprio(1);
#pragma unroll
    for (int m = 0; m < 8; ++m)
#pragma unroll
      for (int n = 0; n < 4; ++n)
        acc[m][n] = __builtin_amdgcn_mfma_f32_16x16x32_bf16(aE[m], bE[n], acc[m][n], 0, 0, 0);
    __builtin_amdgcn_s_setprio(0);
    asm volatile("s_waitcnt lgkmcnt(0)" ::: "memory");   // my reads of buf p done
    asm volatile("s_waitcnt vmcnt(0)" ::: "memory");     // STAGE(t+1) landed (1 tile old)
    __builtin_amdgcn_s_barrier();                        // p free to overwrite; 1-p ready
    if (t + 2 < NT) STAGE(t + 2, p)
    if (t + 1 < NT) {
      const char* An = Arow + (1 - p) * 65536;
      const char* Bn = Brow + (1 - p) * 65536;
#pragma unroll
      for (int m = 0; m < 8; ++m) aE[m] = *(const bf16x8*)(An + m * 2048 + oS0);
#pragma unroll
      for (int n = 0; n < 4; ++n) bE[n] = *(const bf16x8*)(Bn + n * 2048 + oS0);
    }
    __builtin_amdgcn_sched_barrier(0);
    __builtin_amdgcn_s_setprio(1);
#pragma unroll
    for (int m = 0; m < 8; ++m)
#pragma unroll
      for (int n = 0; n < 4; ++n)
        acc[m][n] = __builtin_amdgcn_mfma_f32_16x16x32_bf16(aO[m], bO[n], acc[m][n], 0, 0, 0);
    __builtin_amdgcn_s_setprio(0);
  }
#undef STAGE

  bf16_t* Cb = Cb0 + (size_t)z * strC;
  const long orow = brow + wr * 128 + (lane >> 4) * 4;  // C/D: col=lane&15, row=(lane>>4)*4+reg
  const long ocol = bcol + wc * 64 + l16;
#pragma unroll
  for (int m = 0; m < 8; ++m) {
#pragma unroll
    for (int reg = 0; reg < 4; ++reg) {
      const long r = orow + m * 16 + reg;
#pragma unroll
      for (int n = 0; n < 4; ++n) {
        const size_t idx = (size_t)r * N + ocol + n * 16;
        const float v = acc[m][n][reg];
        if constexpr (EPI == 0) {
          Cb[idx] = __float2bfloat16(v);
        } else if constexpr (EPI == 1) {
          Cf[idx] = addf[idx] + v;
        } else if constexpr (EPI == 2) {
          float u = v > 0.f ? v : 0.f;
          Cb[idx] = __float2bfloat16(u * u);
        } else if constexpr (EPI == 3) {
          Cb[idx] = __float2bfloat16(1.f / (1.f + __expf(-v)));
        } else if constexpr (EPI == 4) {
          Cf[idx] = v;
        } else {
          Cf[idx] = addf[idx] + __bfloat162float(mulb[idx]) * (Cf[idx] + v);
        }
      }
    }
  }
}

extern "C" void kernel_launch(void* const* d_in, const int* in_sizes, int n_in,
                              void* d_out, int out_size, void* d_ws, size_t ws_size,
                              hipStream_t stream) {
  const float* x    = (const float*)d_in[0];
  const float* ln1g = (const float*)d_in[1];
  const float* ln1b = (const float*)d_in[2];
  const float* Wk   = (const float*)d_in[3];
  const float* Wv   = (const float*)d_in[4];
  const float* Wr   = (const float*)d_in[5];
  const float* Wo   = (const float*)d_in[6];
  const float* td   = (const float*)d_in[7];
  const float* tf   = (const float*)d_in[8];
  const float* mk   = (const float*)d_in[9];
  const float* mv   = (const float*)d_in[10];
  const float* mr   = (const float*)d_in[11];
  const float* ln2g = (const float*)d_in[12];
  const float* ln2b = (const float*)d_in[13];
  const float* Wfk  = (const float*)d_in[14];
  const float* Wfv  = (const float*)d_in[15];
  const float* Wfr  = (const float*)d_in[16];

  char* ws = (char*)d_ws;
  const size_t MB = 1ull << 20;
  bf16_t* WkT  = (bf16_t*)(ws + 0 * MB);
  bf16_t* WvT  = (bf16_t*)(ws + 2 * MB);
  bf16_t* WrT  = (bf16_t*)(ws + 4 * MB);
  bf16_t* WoT  = (bf16_t*)(ws + 6 * MB);
  bf16_t* WfkT = (bf16_t*)(ws + 8 * MB);    // [4096][1024]
  bf16_t* WfvT = (bf16_t*)(ws + 16 * MB);   // [1024][4096]
  bf16_t* WfrT = (bf16_t*)(ws + 24 * MB);
  bf16_t* xk   = (bf16_t*)(ws + 28 * MB);
  bf16_t* xv   = (bf16_t*)(ws + 60 * MB);
  bf16_t* xr   = (bf16_t*)(ws + 92 * MB);
  bf16_t* kbuf = (bf16_t*)(ws + 124 * MB);
  bf16_t* vbuf = (bf16_t*)(ws + 156 * MB);
  bf16_t* rbuf = (bf16_t*)(ws + 188 * MB);
  float*  segA = (float*)(ws + 60 * MB);
  float*  segB = (float*)(ws + 61 * MB);
  float*  carA = (float*)(ws + 62 * MB);
  float*  carB = (float*)(ws + 63 * MB);
  bf16_t* rwkv = (bf16_t*)(ws + 92 * MB);
  float*  x1   = (float*)(ws + 28 * MB);    // f32 64 MB
  bf16_t* rr   = (bf16_t*)(ws + 92 * MB);
  bf16_t* ynb  = (bf16_t*)(ws + 124 * MB);
  bf16_t* kk   = (bf16_t*)(ws + 124 * MB);  // [16384][2048] bf16 = 64 MB
  bf16_t* ymix = (bf16_t*)(ws + 188 * MB);
  float*  out  = (float*)d_out;
  const long sX = (long)kM * kD;            // 16777216 elems
  const long sW = (long)kD * kD;            // 1048576 elems

  dim3 blk(256), blkg(512);
  // weights -> bf16 B^T
  k_transpose_cast<<<dim3(32, 32), blk, 0, stream>>>(Wk, WkT, 1024, 1024);
  k_transpose_cast<<<dim3(32, 32), blk, 0, stream>>>(Wv, WvT, 1024, 1024);
  k_transpose_cast<<<dim3(32, 32), blk, 0, stream>>>(Wr, WrT, 1024, 1024);
  k_transpose_cast<<<dim3(32, 32), blk, 0, stream>>>(Wo, WoT, 1024, 1024);
  k_transpose_cast<<<dim3(128, 32), blk, 0, stream>>>(Wfk, WfkT, 1024, 4096);
  k_transpose_cast<<<dim3(32, 128), blk, 0, stream>>>(Wfv, WfvT, 4096, 1024);
  k_transpose_cast<<<dim3(32, 32), blk, 0, stream>>>(Wfr, WfrT, 1024, 1024);

  // ---- time mixing ----
  k_ln1f<<<kM, blk, 0, stream>>>(x, ln1g, ln1b, mk, mv, mr, xk, xv, xr);
  gemmT<0><<<dim3(256, 1, 3), blkg, 0, stream>>>(xk, sX, 1024, WkT, sW, 1024,
      kbuf, nullptr, sX, 1024, 1024, 4, nullptr, nullptr);
  k_wkv_seg<<<dim3(4, 8, kSeg), blk, 0, stream>>>((const unsigned short*)kbuf,
      (const unsigned short*)vbuf, td, tf, segA, segB);
  k_wkv_carry<<<dim3(4, 8), blk, 0, stream>>>(td, segA, segB, carA, carB);
  k_wkv_out<<<dim3(4, 8, kSeg), blk, 0, stream>>>((const unsigned short*)kbuf,
      (const unsigned short*)vbuf, (const unsigned short*)rbuf, td, tf, carA, carB,
      (unsigned short*)rwkv);
  gemmT<1><<<256, blkg, 0, stream>>>(rwkv, 0, 1024, WoT, 0, 1024,
      nullptr, x1, 0, 1024, 1024, 4, x, nullptr);

  // ---- channel mixing ----
  k_ln2f<<<kM, blk, 0, stream>>>(x1, ln2g, ln2b, ymix, ynb);
  gemmT<3><<<256, blkg, 0, stream>>>(ynb, 0, 1024, WfrT, 0, 1024,
      rr, nullptr, 0, 1024, 1024, 4, nullptr, nullptr);
  // hidden dim in 2 chunks of 2048: kk = relu(ymix@Wfk[:,c])^2; out (+)= kk@Wfv[c,:]
  for (int c = 0; c < 2; ++c) {
    gemmT<2><<<512, blkg, 0, stream>>>(ymix, 0, 1024, WfkT + (size_t)c * 2048 * 1024, 0, 1024,
        kk, nullptr, 0, 2048, 1024, 8, nullptr, nullptr);
    if (c == 0)
      gemmT<4><<<256, blkg, 0, stream>>>(kk, 0, 2048, WfvT + 0, 0, 4096,
          nullptr, out, 0, 1024, 2048, 4, nullptr, nullptr);
    else
      gemmT<6><<<256, blkg, 0, stream>>>(kk, 0, 2048, WfvT + 2048, 0, 4096,
          nullptr, out, 0, 1024, 2048, 4, x1, rr);
  }
}